// Round 2
// baseline (72.744 us; speedup 1.0000x reference)
//
#include <hip/hip_runtime.h>
#include <math.h>

#define S_ 32
#define B_ 128
#define M_ 128
#define F_ 512
#define C_ 100

// ws layout (floats):
//   eta     [B_*M_]            @ 0
//   epen    float2[C_*M_]      @ B_*M_            (.x=exp(+2b), .y=exp(-2b))
//   partial [ng*B_*M_]         @ B_*M_ + 2*C_*M_  (ng = 32 or 8)
#define WS_ETA  0
#define WS_EPEN (B_*M_)
#define WS_PART (B_*M_ + 2*C_*M_)

// Kernel 1: eta = sigmoid(alpha_0 + x @ alpha.T)  (blocks 0..B_-1)
//           interleaved epen table                (blocks B_..)
__global__ __launch_bounds__(128) void k_eta_tab(
    const float* __restrict__ x, const float* __restrict__ alpha0,
    const float* __restrict__ alpha, const float* __restrict__ beta,
    float* __restrict__ ws) {
  int bid = blockIdx.x;
  int t = threadIdx.x;  // 0..127
  if (bid < B_) {
    __shared__ __align__(16) float xs[F_];
    ((float4*)xs)[t] = ((const float4*)(x + (size_t)bid * F_))[t];
    __syncthreads();
    int m = t;
    const float4* ar = (const float4*)(alpha + (size_t)m * F_);
    float acc = 0.f;
#pragma unroll 4
    for (int j = 0; j < F_ / 4; ++j) {
      float4 a = ar[j];
      float4 xv = ((const float4*)xs)[j];
      acc = fmaf(a.x, xv.x, acc);
      acc = fmaf(a.y, xv.y, acc);
      acc = fmaf(a.z, xv.z, acc);
      acc = fmaf(a.w, xv.w, acc);
    }
    float l = alpha0[m] + acc;
    ws[WS_ETA + bid * M_ + m] = 1.f / (1.f + expf(-l));
  } else {
    int i = (bid - B_) * 128 + t;  // C_*M_ = 12800 slots, linear c*M_+m order
    if (i < C_ * M_) {
      float bv = beta[i];
      float2* epen = (float2*)(ws + WS_EPEN);
      epen[i] = make_float2(expf(2.f * bv), expf(-2.f * bv));
    }
  }
}

// Kernel 2: grid (ng, B_/4), block 512. Each 128-thread sub-block owns one b;
// loops over sg = S_/ng samples. Wave-level shfl reductions; 4 barriers/sample.
__global__ __launch_bounds__(512) void k_contrib(
    const float* __restrict__ Z, const int* __restrict__ y,
    const float* __restrict__ beta0, const float* __restrict__ beta,
    const float* __restrict__ ws, float* __restrict__ partial, int sg) {
  int g = blockIdx.x;                 // s-group
  int bq = blockIdx.y;                // b-quad
  int t = threadIdx.x;                // 0..511
  int bl = t >> 7;                    // 0..3 sub-block (one b each)
  int m = t & 127;                    // m index; doubles as c index (c<100)
  int b = bq * 4 + bl;
  int w = t >> 6;                     // wave id 0..7

  const float* eta = ws + WS_ETA;
  const float2* epen = (const float2*)(ws + WS_EPEN);

  __shared__ __align__(16) float zsh[4][M_];
  __shared__ float esh[4][M_];
  __shared__ float redmax[8];
  __shared__ float redsum[8];

  int yb = y[b];
  float eta_bm = eta[b * M_ + m];
  float one_m_eta = 1.f - eta_bm;
  float acc = 0.f;

  for (int si = 0; si < sg; ++si) {
    int s = g * sg + si;
    zsh[bl][m] = Z[((size_t)s * B_ + b) * M_ + m];
    __syncthreads();  // (1) zsh visible to sub-block

    // base[c] = beta_0[c] + sum_m Z[s,b,m] * beta[c,m]   (c = m, c < C_)
    float base = -1e30f;
    if (m < C_) {
      const float4* br = (const float4*)(beta + (size_t)m * M_);
      const float4* z4 = (const float4*)zsh[bl];
      float a = 0.f;
#pragma unroll
      for (int j = 0; j < M_ / 4; ++j) {
        float4 bb = br[j];
        float4 zz = z4[j];
        a = fmaf(bb.x, zz.x, a);
        a = fmaf(bb.y, zz.y, a);
        a = fmaf(bb.z, zz.z, a);
        a = fmaf(bb.w, zz.w, a);
      }
      base = beta0[m] + a;
    }

    // max over c: wave butterfly, then combine the sub-block's 2 waves
    float v = base;
#pragma unroll
    for (int off = 32; off > 0; off >>= 1) v = fmaxf(v, __shfl_xor(v, off));
    if ((t & 63) == 0) redmax[w] = v;
    __syncthreads();  // (2)
    float mb = fmaxf(redmax[bl * 2], redmax[bl * 2 + 1]);

    float e0 = (m < C_) ? expf(base - mb) : 0.f;
    esh[bl][m] = e0;
    float sv = e0;
#pragma unroll
    for (int off = 32; off > 0; off >>= 1) sv += __shfl_xor(sv, off);
    if ((t & 63) == 0) redsum[w] = sv;
    __syncthreads();  // (3) redsum + esh visible
    float den0 = redsum[bl * 2] + redsum[bl * 2 + 1];
    float e0y = esh[bl][yb];
    float pi0 = e0y / den0;

    // den_p/den_n for this m: sum_c E0[c] * exp(+/-2*beta[c,m])
    float accp = 0.f, accn = 0.f;
#pragma unroll 4
    for (int c = 0; c < C_; ++c) {
      float e = esh[bl][c];
      float2 pe = epen[c * M_ + m];
      accp = fmaf(e, pe.x, accp);
      accn = fmaf(e, pe.y, accn);
    }

    float z = zsh[bl][m];
    float2 pey = epen[yb * M_ + m];
    float contrib;
    if (z > 0.f) {
      float pin = e0y * pey.y / accn;
      contrib = fmaf(pi0, eta_bm, pin * one_m_eta);
    } else {
      float pip = e0y * pey.x / accp;
      contrib = fmaf(pip, eta_bm, pi0 * one_m_eta);
    }
    acc += contrib;
    __syncthreads();  // (4) protect zsh/esh/redmax before next sample
  }

  partial[((size_t)g * B_ + b) * M_ + m] = acc;
}

// Kernel 3: out[b,m] = sum_g partial[g][b][m]
__global__ __launch_bounds__(256) void k_reduce(const float* __restrict__ partial,
                                                float* __restrict__ out, int ng) {
  int i = blockIdx.x * 256 + threadIdx.x;
  if (i < B_ * M_) {
    float a = 0.f;
    for (int gi = 0; gi < ng; ++gi) a += partial[(size_t)gi * B_ * M_ + i];
    out[i] = a;
  }
}

extern "C" void kernel_launch(void* const* d_in, const int* in_sizes, int n_in,
                              void* d_out, int out_size, void* d_ws, size_t ws_size,
                              hipStream_t stream) {
  const float* x = (const float*)d_in[0];
  const int* y = (const int*)d_in[1];
  const float* Z = (const float*)d_in[2];
  const float* alpha0 = (const float*)d_in[3];
  const float* alpha = (const float*)d_in[4];
  const float* beta0 = (const float*)d_in[5];
  const float* beta = (const float*)d_in[6];
  float* ws = (float*)d_ws;
  float* out = (float*)d_out;
  float* partial = ws + WS_PART;

  // Deterministic ws-size gate: prefer 32 independent s-groups (full occupancy),
  // fall back to 8 groups x 4 serial samples if ws is small.
  size_t need32 = (size_t)(WS_PART + 32 * B_ * M_) * sizeof(float);
  int ng, sg;
  if (ws_size >= need32) { ng = 32; sg = 1; } else { ng = 8; sg = 4; }

  k_eta_tab<<<dim3(B_ + (C_ * M_ + 127) / 128), dim3(128), 0, stream>>>(
      x, alpha0, alpha, beta, ws);
  k_contrib<<<dim3(ng, B_ / 4), dim3(512), 0, stream>>>(Z, y, beta0, beta, ws,
                                                        partial, sg);
  k_reduce<<<dim3((B_ * M_ + 255) / 256), dim3(256), 0, stream>>>(partial, out, ng);
}

// Round 3
// 30.339 us; speedup vs baseline: 2.3977x; 2.3977x over previous
//
#include <hip/hip_runtime.h>
#include <math.h>

#define S_ 32
#define B_ 128
#define M_ 128
#define F_ 512
#define C_ 100
#define MH 64    // m-half per block
#define PSTR 36  // Psh4 row stride in floats (16B-aligned rows, bank-spread)

// One fused kernel. Grid (2, 128): blockIdx.x = m-half, blockIdx.y = b.
// 512 threads = 8 waves; wave g owns pairs p = g*4..g*4+3 in phases C/D.
__global__ __launch_bounds__(512, 1) void k_main(
    const float* __restrict__ x, const int* __restrict__ y,
    const float* __restrict__ Z, const float* __restrict__ alpha0,
    const float* __restrict__ alpha, const float* __restrict__ beta0,
    const float* __restrict__ beta, float* __restrict__ out) {
  const int mh = blockIdx.x;   // 0,1
  const int b = blockIdx.y;    // 0..127
  const int tid = threadIdx.x;
  const int lane = tid & 63;
  const int g = tid >> 6;      // wave 0..7

  __shared__ __align__(16) float ep_lds[C_ * MH];   // 25.6 KB  exp(+2*beta[c][m-half])
  __shared__ __align__(16) float en_lds[C_ * MH];   // 25.6 KB  exp(-2*beta[c][m-half])
  __shared__ __align__(16) float zsh[S_ * M_];      // 16 KB    Z rows, float4-slot swizzled
  __shared__ __align__(16) float bsh[S_ * M_];      // 16 KB    base[p][c]
  __shared__ __align__(16) float Psh4[C_ * PSTR];   // 14.4 KB  softmax P, [c][p] padded
  __shared__ float Pyb[S_];
  __shared__ float esh_eta[MH];
  __shared__ float red[8 * MH];                     // 2 KB

  // ---------------- Phase A: staging ----------------
  const int yb = y[b];

  // Z rows for this b (all 32 s, full m). Swizzle float4 slots so phase-B's
  // 4-distinct-address broadcasts land on 4 distinct bank quads:
  // element (p, m): q=m>>5, i4=(m>>2)&7, j=m&3 -> word p*128 + q*32 + ((i4^q)<<2) + j
#pragma unroll
  for (int k = 0; k < 8; ++k) {
    int i = tid + k * 512;           // 0..4095
    int p = i >> 7, m = i & 127;
    int qq = m >> 5, i4 = (m >> 2) & 7, jj = m & 3;
    zsh[p * 128 + qq * 32 + ((i4 ^ qq) << 2) + jj] =
        Z[((size_t)p * B_ + b) * M_ + m];
  }

  // ep/en for this m-half, computed from beta directly (no global table)
  for (int i = tid; i < C_ * MH; i += 512) {
    int c = i >> 6, mm = i & 63;
    float bv = beta[c * M_ + mh * MH + mm];
    ep_lds[i] = expf(2.f * bv);
    en_lds[i] = expf(-2.f * bv);
  }

  // beta row-slice into registers for phase B: thread (cc = tid>>2, q = tid&3)
  // owns beta[cc][q*32 .. q*32+31] as 8 float4 (one-time scattered load).
  const int cc = tid >> 2;  // 0..127 (cc >= C_ inert)
  const int q = tid & 3;
  float4 br[8];
  float b0r = 0.f;
  if (cc < C_) {
    const float4* beta4 = (const float4*)beta;
#pragma unroll
    for (int i4 = 0; i4 < 8; ++i4) br[i4] = beta4[cc * 32 + q * 8 + i4];
    b0r = beta0[cc];
  } else {
#pragma unroll
    for (int i4 = 0; i4 < 8; ++i4) br[i4] = make_float4(0.f, 0.f, 0.f, 0.f);
  }

  // eta for this block's 64 m values — coalesced lanes-over-f wave-GEMV.
  {
    const float4* x4 = (const float4*)x;
    float4 xa = x4[b * 128 + lane];
    float4 xb = x4[b * 128 + 64 + lane];
    const float4* a4 = (const float4*)alpha;
#pragma unroll
    for (int j = 0; j < 8; ++j) {
      int m = mh * MH + g * 8 + j;
      float4 a1 = a4[(size_t)m * 128 + lane];
      float4 a2 = a4[(size_t)m * 128 + 64 + lane];
      float acc = 0.f;
      acc = fmaf(a1.x, xa.x, acc); acc = fmaf(a1.y, xa.y, acc);
      acc = fmaf(a1.z, xa.z, acc); acc = fmaf(a1.w, xa.w, acc);
      acc = fmaf(a2.x, xb.x, acc); acc = fmaf(a2.y, xb.y, acc);
      acc = fmaf(a2.z, xb.z, acc); acc = fmaf(a2.w, xb.w, acc);
#pragma unroll
      for (int off = 32; off > 0; off >>= 1) acc += __shfl_xor(acc, off);
      if (lane == 0) {
        float l = alpha0[m] + acc;
        esh_eta[g * 8 + j] = 1.f / (1.f + expf(-l));
      }
    }
  }

  __syncthreads();  // zsh (and esh_eta/ep/en ordering for later phases)

  // ---------------- Phase B: base[p][c] ----------------
  // thread (cc,q): partial dot over its 32 m; reduce over q via 2 shfl.
  {
    const float4* zsh4 = (const float4*)zsh;
#pragma unroll 4
    for (int p = 0; p < S_; ++p) {
      float acc = 0.f;
#pragma unroll
      for (int i4 = 0; i4 < 8; ++i4) {
        float4 zv = zsh4[p * 32 + q * 8 + (i4 ^ q)];
        float4 bb = br[i4];
        acc = fmaf(bb.x, zv.x, acc);
        acc = fmaf(bb.y, zv.y, acc);
        acc = fmaf(bb.z, zv.z, acc);
        acc = fmaf(bb.w, zv.w, acc);
      }
      float r = acc + __shfl_xor(acc, 1);
      r = r + __shfl_xor(r, 2);
      if (q == 0) bsh[p * 128 + cc] = r + b0r;
    }
  }
  __syncthreads();  // bsh ready

  // ---------------- Phase C: softmax per pair; wave g -> p = g*4+k ----------------
  {
    int c0 = lane;  // 0..63
#pragma unroll
    for (int k = 0; k < 4; ++k) {
      int p = g * 4 + k;
      float v1 = bsh[p * 128 + c0];
      bool has2 = (c0 + 64) < C_;
      float v2 = has2 ? bsh[p * 128 + c0 + 64] : -INFINITY;
      float mx = fmaxf(v1, v2);
#pragma unroll
      for (int off = 32; off > 0; off >>= 1) mx = fmaxf(mx, __shfl_xor(mx, off));
      float e1 = expf(v1 - mx);
      float e2 = has2 ? expf(v2 - mx) : 0.f;
      float sm = e1 + e2;
#pragma unroll
      for (int off = 32; off > 0; off >>= 1) sm += __shfl_xor(sm, off);
      float rd = 1.f / sm;
      float p1 = e1 * rd, p2 = e2 * rd;
      Psh4[c0 * PSTR + p] = p1;
      if (has2) Psh4[(c0 + 64) * PSTR + p] = p2;
      if (c0 == yb) Pyb[p] = p1;
      if (c0 + 64 == yb) Pyb[p] = p2;
    }
  }
  __syncthreads();  // Psh4, Pyb ready (ep/en, esh_eta covered too)

  // ---------------- Phase D: den_p/den_n + contributions ----------------
  // thread (g, lane): m = mh*64 + lane, pairs p = g*4..g*4+3.
  float ap0 = 0.f, ap1 = 0.f, ap2 = 0.f, ap3 = 0.f;
  float an0 = 0.f, an1 = 0.f, an2 = 0.f, an3 = 0.f;
  {
    const float4* P4 = (const float4*)Psh4;  // float4 index: c*9 + g
#pragma unroll 4
    for (int c = 0; c < C_; ++c) {
      float epv = ep_lds[c * MH + lane];
      float env = en_lds[c * MH + lane];
      float4 pv = P4[c * 9 + g];
      ap0 = fmaf(pv.x, epv, ap0); an0 = fmaf(pv.x, env, an0);
      ap1 = fmaf(pv.y, epv, ap1); an1 = fmaf(pv.y, env, an1);
      ap2 = fmaf(pv.z, epv, ap2); an2 = fmaf(pv.z, env, an2);
      ap3 = fmaf(pv.w, epv, ap3); an3 = fmaf(pv.w, env, an3);
    }
  }
  // epilogue
  {
    float eta_v = esh_eta[lane];
    float ome = 1.f - eta_v;
    float epy = ep_lds[yb * MH + lane];
    float eny = en_lds[yb * MH + lane];
    int mfull = mh * MH + lane;
    int qz = mfull >> 5, i4z = (mfull >> 2) & 7, jz = mfull & 3;
    int zoff = qz * 32 + ((i4z ^ qz) << 2) + jz;
    float o = 0.f;
    float ap[4] = {ap0, ap1, ap2, ap3};
    float an[4] = {an0, an1, an2, an3};
#pragma unroll
    for (int k = 0; k < 4; ++k) {
      int p = g * 4 + k;
      float z = zsh[p * 128 + zoff];
      float pyb = Pyb[p];
      float contrib;
      if (z > 0.f) {
        float pin = pyb * eny / an[k];
        contrib = fmaf(pyb, eta_v, pin * ome);   // pi0*eta + pi_neg*(1-eta)
      } else {
        float pip = pyb * epy / ap[k];
        contrib = fmaf(pip, eta_v, pyb * ome);   // pi_pos*eta + pi0*(1-eta)
      }
      o += contrib;
    }
    red[g * MH + lane] = o;
  }
  __syncthreads();

  if (tid < MH) {
    float ssum = 0.f;
#pragma unroll
    for (int gg = 0; gg < 8; ++gg) ssum += red[gg * MH + tid];
    out[b * M_ + mh * MH + tid] = ssum;
  }
}

extern "C" void kernel_launch(void* const* d_in, const int* in_sizes, int n_in,
                              void* d_out, int out_size, void* d_ws, size_t ws_size,
                              hipStream_t stream) {
  const float* x = (const float*)d_in[0];
  const int* y = (const int*)d_in[1];
  const float* Z = (const float*)d_in[2];
  const float* alpha0 = (const float*)d_in[3];
  const float* alpha = (const float*)d_in[4];
  const float* beta0 = (const float*)d_in[5];
  const float* beta = (const float*)d_in[6];
  float* out = (float*)d_out;

  k_main<<<dim3(2, B_), dim3(512), 0, stream>>>(x, y, Z, alpha0, alpha, beta0,
                                                beta, out);
}